// Round 4
// baseline (484.506 us; speedup 1.0000x reference)
//
#include <hip/hip_runtime.h>
#include <math.h>

#define BSZ 32
#define NP  1024

// ---- workspace layout (float offsets) ----
#define OFF_ACC   0                          // acc[0]=sum(logR-S), [1]=sum S, [2]=sum T*logC, [3]=corr, [4]=chamfer
#define OFF_COS   8                          // dot[32], n1[32], n2[32]
#define OFF_POSE  104                        // 24 floats per batch
#define OFF_P1IN2 872
#define OFF_P2IN1 (OFF_P1IN2 + 98304)
#define OFF_COLP  (OFF_P2IN1 + 98304)        // colP[2048 blocks][2048] = 4M floats (16 MB)

// ---------------- pose + accumulator zeroing ----------------
__global__ void k_pose(const float* __restrict__ scale,
                       const float* __restrict__ rot,
                       const float* __restrict__ tr,
                       float* __restrict__ ws) {
    int t = threadIdx.x;                 // 64 threads
    if (t < 52) {                        // zero acc[8] + cosacc[96]
        ws[OFF_ACC + 2 * t]     = 0.f;
        ws[OFF_ACC + 2 * t + 1] = 0.f;
    }
    if (t >= BSZ) return;
    int b = t;
    float s = scale[b];
    float M[9];
#pragma unroll
    for (int i = 0; i < 9; ++i) M[i] = rot[b * 9 + i] * s;
    float t0 = tr[b * 3 + 0], t1 = tr[b * 3 + 1], t2 = tr[b * 3 + 2];
    float det = M[0] * (M[4] * M[8] - M[5] * M[7])
              - M[1] * (M[3] * M[8] - M[5] * M[6])
              + M[2] * (M[3] * M[7] - M[4] * M[6]);
    float id = 1.0f / det;
    float inv[9];
    inv[0] =  (M[4] * M[8] - M[5] * M[7]) * id;
    inv[1] = -(M[1] * M[8] - M[2] * M[7]) * id;
    inv[2] =  (M[1] * M[5] - M[2] * M[4]) * id;
    inv[3] = -(M[3] * M[8] - M[5] * M[6]) * id;
    inv[4] =  (M[0] * M[8] - M[2] * M[6]) * id;
    inv[5] = -(M[0] * M[5] - M[2] * M[3]) * id;
    inv[6] =  (M[3] * M[7] - M[4] * M[6]) * id;
    inv[7] = -(M[0] * M[7] - M[1] * M[6]) * id;
    inv[8] =  (M[0] * M[4] - M[1] * M[3]) * id;
    float u0 = -(inv[0] * t0 + inv[1] * t1 + inv[2] * t2);
    float u1 = -(inv[3] * t0 + inv[4] * t1 + inv[5] * t2);
    float u2 = -(inv[6] * t0 + inv[7] * t1 + inv[8] * t2);
    float* P = ws + OFF_POSE + b * 24;
#pragma unroll
    for (int i = 0; i < 9; ++i) P[i] = M[i];
    P[9] = t0; P[10] = t1; P[11] = t2;
#pragma unroll
    for (int i = 0; i < 9; ++i) P[12 + i] = inv[i];
    P[21] = u0; P[22] = u1; P[23] = u2;
}

// ---------------- single fused pass: one matrix per block ----------------
// grid: 2048 = b(32) * m(2) * rb(32); 256 thr = 4 waves * 8 rows/wave.
// Per block: row softmax stats + column partials (C/T in 32 regs) + own norm;
// m==0 blocks also stream the matching am2 tile for the cos dot (L3-resident:
// the m==1 block with same (b,rb) reads the same tile).
// Points (one side, 12 KB) in LDS, conflict-free permuted SoA.
__global__ __launch_bounds__(256) void k_main(
    const float* __restrict__ am1, const float* __restrict__ am2,
    const float* __restrict__ pts1, const float* __restrict__ pts2,
    float* __restrict__ p1in2, float* __restrict__ p2in1,
    float* __restrict__ colP, float* __restrict__ cosacc, float* __restrict__ acc) {
    __shared__ float ptsL[3072];     // [dim][ perm(c) ]
    __shared__ float cacc[2048];     // C[1024], T[1024] block partials
    __shared__ float sred[16];
    const int bid = blockIdx.x;
    const int rb = bid & 31;
    const int m  = (bid >> 5) & 1;
    const int b  = bid >> 6;
    const int wv = threadIdx.x >> 6, ln = threadIdx.x & 63;
    const int row0 = rb * 32 + wv * 8;
    const float* am  = m ? am2 : am1;
    const float* pts = m ? pts1 : pts2;     // mat1 pairs with points_2, mat2 with points_1
    float* pout = m ? p2in1 : p1in2;

    for (int i = threadIdx.x; i < 2048; i += 256) cacc[i] = 0.f;
    // stage points: coalesced global read, permuted LDS write (one-time).
    // perm(c) = 256*(c&3) + (c>>2)  ->  element (j,k) of lane ln sits at 256k+64j+ln.
    for (int t = threadIdx.x; t < 3072; t += 256) {
        int c = t / 3, d = t - 3 * c;
        ptsL[d * 1024 + 256 * (c & 3) + (c >> 2)] = pts[b * 3072 + t];
    }
    __syncthreads();

    float C[16], T[16];
#pragma unroll
    for (int i = 0; i < 16; ++i) { C[i] = 0.f; T[i] = 0.f; }
    float e2a = 0.f, sSa = 0.f, dacc = 0.f, na = 0.f;

    const float4* rA = (const float4*)(am  + ((size_t)b * NP + row0) * NP);
    const float4* rB = (const float4*)(am2 + ((size_t)b * NP + row0) * NP);

#pragma unroll 1
    for (int r = 0; r < 8; ++r) {
        float4 a[4];
#pragma unroll
        for (int j = 0; j < 4; ++j) a[j] = rA[(size_t)r * 256 + ln + 64 * j];
        // own-norm partial (n1 from m0 blocks, n2 from m1 blocks)
#pragma unroll
        for (int j = 0; j < 4; ++j)
            na += a[j].x * a[j].x + a[j].y * a[j].y + a[j].z * a[j].z + a[j].w * a[j].w;
        // cos dot: only m==0 blocks read the matching am2 tile
        if (m == 0) {
#pragma unroll
            for (int j = 0; j < 4; ++j) {
                float4 c4 = rB[(size_t)r * 256 + ln + 64 * j];
                dacc += a[j].x * c4.x + a[j].y * c4.y + a[j].z * c4.z + a[j].w * c4.w;
            }
        }
        float R = 0.f, Su = 0.f, q0 = 0.f, q1 = 0.f, q2 = 0.f;
#pragma unroll
        for (int j = 0; j < 4; ++j) {
            float* e = (float*)&a[j];
#pragma unroll
            for (int k = 0; k < 4; ++k) {
                int i = 4 * j + k;
                int pidx = 256 * k + 64 * j + ln;
                float v  = e[k];
                float ex = __expf(v);
                R += ex; Su += ex * v;
                q0 += ex * ptsL[pidx];
                q1 += ex * ptsL[1024 + pidx];
                q2 += ex * ptsL[2048 + pidx];
                C[i] += ex;
                e[k] = ex;
            }
        }
#pragma unroll
        for (int s = 1; s < 64; s <<= 1) {
            R  += __shfl_xor(R, s);  Su += __shfl_xor(Su, s);
            q0 += __shfl_xor(q0, s); q1 += __shfl_xor(q1, s); q2 += __shfl_xor(q2, s);
        }
        float inv = 1.0f / R;
#pragma unroll
        for (int j = 0; j < 4; ++j) {
            float* e = (float*)&a[j];
#pragma unroll
            for (int k = 0; k < 4; ++k) T[4 * j + k] += e[k] * inv;
        }
        float S = Su * inv;
        if (ln == 0) {
            e2a += __logf(R) - S;
            sSa += S;
            int row = row0 + r;
            float* o = pout + ((size_t)b * NP + row) * 3;
            o[0] = q0 * inv; o[1] = q1 * inv; o[2] = q2 * inv;
        }
    }

    // flush C/T to block-level LDS partials (4-wave contention max)
#pragma unroll
    for (int j = 0; j < 4; ++j)
#pragma unroll
        for (int k = 0; k < 4; ++k) {
            int i = 4 * j + k;
            int c = 256 * j + 4 * ln + k;
            atomicAdd(&cacc[c],        C[i]);
            atomicAdd(&cacc[1024 + c], T[i]);
        }
#pragma unroll
    for (int s = 1; s < 64; s <<= 1) {
        dacc += __shfl_xor(dacc, s);
        na   += __shfl_xor(na, s);
    }
    if (ln == 0) { sred[wv] = e2a; sred[4 + wv] = sSa; sred[8 + wv] = dacc; sred[12 + wv] = na; }
    __syncthreads();
    if (threadIdx.x == 0) {
        atomicAdd(&acc[0], sred[0] + sred[1] + sred[2] + sred[3]);
        atomicAdd(&acc[1], sred[4] + sred[5] + sred[6] + sred[7]);
        if (m == 0) {
            atomicAdd(&cosacc[b],      sred[8]  + sred[9]  + sred[10] + sred[11]);
            atomicAdd(&cosacc[32 + b], sred[12] + sred[13] + sred[14] + sred[15]);
        } else {
            atomicAdd(&cosacc[64 + b], sred[12] + sred[13] + sred[14] + sred[15]);
        }
    }
    // stream block partials (plain coalesced stores)
    float4* cp = (float4*)(colP + (size_t)bid * 2048);
    const float4* cs = (const float4*)cacc;
    for (int i = threadIdx.x; i < 512; i += 256) cp[i] = cs[i];
}

// ---------------- reduce column partials: sum T * log C ----------------
__global__ void k_colred(const float* __restrict__ colP, float* __restrict__ acc) {
    int idx = blockIdx.x * 256 + threadIdx.x;   // 65536 = bm(64) * c(1024)
    int bm = idx >> 10;                         // b*2 + m  (matches bid>>5)
    int c  = idx & 1023;
    const float* base = colP + (size_t)bm * 32 * 2048 + c;
    float C = 0.f, T = 0.f;
#pragma unroll
    for (int rbi = 0; rbi < 32; ++rbi) {
        C += base[(size_t)rbi * 2048];
        T += base[(size_t)rbi * 2048 + 1024];
    }
    float v = T * __logf(C);
#pragma unroll
    for (int s = 1; s < 64; s <<= 1) v += __shfl_xor(v, s);
    if ((threadIdx.x & 63) == 0) atomicAdd(&acc[2], v);
}

// ---------------- chamfer + Huber corr, transforms on the fly ----------------
// grid: pair(2) * dir(2) * b(32) * chunk(4) = 512 blocks, 256 threads, 1 X point/thread
__global__ __launch_bounds__(256) void k_cham(
    const float* __restrict__ p1, const float* __restrict__ p2,
    const float* __restrict__ p1in2, const float* __restrict__ p2in1,
    const float* __restrict__ pose, float* __restrict__ acc) {
    __shared__ float4 ys[NP];
    const int blk   = blockIdx.x;
    const int chunk = blk & 3;
    const int b     = (blk >> 2) & 31;
    const int dir   = (blk >> 7) & 1;
    const int pair  = blk >> 8;
    const float* P   = pose + b * 24 + pair * 12;   // fwd pose for pair0, inverse for pair1
    const float* raw = pair ? p2 : p1;
    const float* inA = pair ? p2in1 : p1in2;
    const int t = threadIdx.x;

    float m0 = P[0], m1 = P[1], m2 = P[2];
    float m3 = P[3], m4 = P[4], m5 = P[5];
    float m6 = P[6], m7 = P[7], m8 = P[8];
    float t0 = P[9], t1 = P[10], t2 = P[11];

    // stage Y set (1024 points, with |y|^2) into LDS
#pragma unroll
    for (int i = 0; i < 4; ++i) {
        int q = t + 256 * i;
        int gi = (b * NP + q) * 3;
        float x, y, z;
        if (dir == 0) { x = inA[gi]; y = inA[gi + 1]; z = inA[gi + 2]; }
        else {
            float rx = raw[gi], ry = raw[gi + 1], rz = raw[gi + 2];
            x = m0 * rx + m1 * ry + m2 * rz + t0;
            y = m3 * rx + m4 * ry + m5 * rz + t1;
            z = m6 * rx + m7 * ry + m8 * rz + t2;
        }
        ys[q] = make_float4(x, y, z, x * x + y * y + z * z);
    }
    __syncthreads();

    // this thread's X point
    int xi = chunk * 256 + t;
    int gx = (b * NP + xi) * 3;
    float x0, x1, x2;
    if (dir == 0) {
        float rx = raw[gx], ry = raw[gx + 1], rz = raw[gx + 2];
        x0 = m0 * rx + m1 * ry + m2 * rz + t0;
        x1 = m3 * rx + m4 * ry + m5 * rz + t1;
        x2 = m6 * rx + m7 * ry + m8 * rz + t2;
    } else { x0 = inA[gx]; x1 = inA[gx + 1]; x2 = inA[gx + 2]; }
    float sx = x0 * x0 + x1 * x1 + x2 * x2;

    float mn = 3.0e38f;
#pragma unroll 4
    for (int o = 0; o < NP; ++o) {
        float4 yv = ys[o];   // broadcast read, conflict-free
        float d = fmaf(-2.0f, x0 * yv.x + x1 * yv.y + x2 * yv.z, sx + yv.w);
        mn = fminf(mn, d);
    }
    mn = fmaxf(mn, 0.0f);    // clamp commutes with min

    float v = mn;
#pragma unroll
    for (int m = 1; m < 64; m <<= 1) v += __shfl_xor(v, m);
    if ((t & 63) == 0) atomicAdd(&acc[4], v);

    if (dir == 0) {          // Huber corr: A = inA (ys), P-set = transformed X
        float4 a = ys[xi];
        float s = 0.f;
        float d0 = fabsf(a.x - x0); s += (d0 > 0.1f) ? (d0 - 0.05f) : (d0 * d0 * 5.0f);
        float d1 = fabsf(a.y - x1); s += (d1 > 0.1f) ? (d1 - 0.05f) : (d1 * d1 * 5.0f);
        float d2 = fabsf(a.z - x2); s += (d2 > 0.1f) ? (d2 - 0.05f) : (d2 * d2 * 5.0f);
#pragma unroll
        for (int m = 1; m < 64; m <<= 1) s += __shfl_xor(s, m);
        if ((t & 63) == 0) atomicAdd(&acc[3], s);
    }
}

// ---------------- finalize ----------------
__global__ void k_final(const float* __restrict__ acc, const float* __restrict__ cosacc,
                        float* __restrict__ out) {
    if (threadIdx.x != 0) return;
    const float invBN = 1.0f / 32768.0f;
    float ent2 = 1e-4f * acc[0] * invBN;
    float ent1 = 1e-4f * (acc[2] - acc[1]) * invBN;
    float corr = acc[3] * invBN;
    float cham = acc[4] * invBN;
    float cosl = 0.f;
    for (int b = 0; b < 32; ++b) {
        float dot = cosacc[b];
        float na = fmaxf(sqrtf(cosacc[32 + b]), 1e-8f);
        float nb = fmaxf(sqrtf(cosacc[64 + b]), 1e-8f);
        cosl += 1.0f - dot / (na * nb);
    }
    cosl *= (1.0f / 32.0f);
    out[0] = cham + corr + ent2 + ent1 + cosl;
}

extern "C" void kernel_launch(void* const* d_in, const int* in_sizes, int n_in,
                              void* d_out, int out_size, void* d_ws, size_t ws_size,
                              hipStream_t stream) {
    const float* p1    = (const float*)d_in[0];
    const float* p2    = (const float*)d_in[1];
    const float* am1   = (const float*)d_in[2];
    const float* am2   = (const float*)d_in[3];
    const float* scale = (const float*)d_in[4];
    const float* rot   = (const float*)d_in[5];
    const float* tr    = (const float*)d_in[6];

    float* ws = (float*)d_ws;
    float* acc    = ws + OFF_ACC;
    float* cosacc = ws + OFF_COS;
    float* pose   = ws + OFF_POSE;
    float* p1in2  = ws + OFF_P1IN2;
    float* p2in1  = ws + OFF_P2IN1;
    float* colP   = ws + OFF_COLP;

    k_pose<<<1, 64, 0, stream>>>(scale, rot, tr, ws);
    k_main<<<2048, 256, 0, stream>>>(am1, am2, p1, p2, p1in2, p2in1, colP, cosacc, acc);
    k_colred<<<256, 256, 0, stream>>>(colP, acc);
    k_cham<<<512, 256, 0, stream>>>(p1, p2, p1in2, p2in1, pose, acc);
    k_final<<<1, 64, 0, stream>>>(acc, cosacc, (float*)d_out);
}